// Round 1
// baseline (601.434 us; speedup 1.0000x reference)
//
#include <hip/hip_runtime.h>

// out[b,k,n,m] = clip(exp(-0.1*sqrt(max(|An|^2 - 2 An.Am + |Am|^2, 1e-6))), 0, 1)
// x: (8,64,512,16) fp32, msk: (8,64,512,1) fp32, out: (8,64,512,512,1) fp32 (512 MiB).
//
// v2: Gram matrix moved from the vector ALU to the matrix pipe.
//  - The Gram is a (128x16)x(16x128) GEMM per tile with K=16, an exact fit for
//    v_mfma_f32_16x16x16_f16. Inputs converted to fp16 once during LDS staging.
//  - Precision: na is computed from the SAME fp16-converted values, so the
//    na_n + na_m - 2G cancellation stays correlated (diagonal -> s==0 -> eps,
//    near pairs -> s = |a_hat - b_hat|^2 >= 0). fp16 products accumulate in f32
//    inside the MFMA; worst-case added dm error ~1e-3.
//  - Gram A·A^T: the MFMA B-fragment (B[k][j]=A[j][k]) has the SAME lane layout
//    as the A-fragment -> both load as one ds_read_b64 per fragment:
//    lane l reads node base+(l&15), features 4*(l>>4)..+3.
//  - Operand swap (A-operand = m-nodes) so D[row=4q+r][col=l&15] maps to
//    out[n0+ (l&15)][m0'+4q+r]: each lane's 4 acc regs are 4 consecutive output
//    COLUMNS at one output ROW -> direct coalesced f32x4 nontemporal stores.
//  - LDS rows padded to 20 halves (40 B stride): 16-lane fragment groups land
//    on 16 distinct bank pairs (10n mod 32 is a permutation of even banks),
//    so every b64 LDS access runs at the 512B/4-cycle minimum.

typedef float    f32x4 __attribute__((ext_vector_type(4)));
typedef _Float16 f16x4 __attribute__((ext_vector_type(4)));

#define NEG_DIST_LOG2E (-0.14426950408889634f)  // -0.1 * log2(e)
#define EPS_F 1e-6f

__global__ __launch_bounds__(256) void node_pair_gaussian_kernel(
    const float* __restrict__ x,    // (512 slices, 512 nodes, 16 f)
    const float* __restrict__ msk,  // (512 slices, 512 nodes)
    float* __restrict__ out)        // (512 slices, 512, 512)
{
    __shared__ __align__(16) _Float16 lds_n[128][20];  // row tile, fp16, padded
    __shared__ __align__(16) _Float16 lds_m[128][20];  // col tile, fp16, padded
    __shared__ __align__(16) float na_n[128];
    __shared__ __align__(16) float na_m[128];

    const int tid   = threadIdx.x;          // 0..255
    const int tile  = blockIdx.x;           // 0..15
    const int slice = blockIdx.y;           // 0..511  (= b*64 + k)
    const int n0 = (tile >> 2) << 7;        // row tile base
    const int m0 = (tile & 3) << 7;         // col tile base

    const float* xs = x   + (size_t)slice * (512 * 16);
    const float* ms = msk + (size_t)slice * 512;

    // ---- Stage both 128x16 tiles into LDS as fp16 (masked), node-major ----
    #pragma unroll
    for (int it = 0; it < 2; ++it) {
        const int task = tid + it * 256;    // 0..511 = 128 nodes x 4 f4-chunks
        const int node = task & 127;
        const int f4   = task >> 7;         // 0..3
        {
            const f32x4 v = *(const f32x4*)(xs + (size_t)(n0 + node) * 16 + f4 * 4);
            const float mm = ms[n0 + node];
            f16x4 h = { (_Float16)(v.x * mm), (_Float16)(v.y * mm),
                        (_Float16)(v.z * mm), (_Float16)(v.w * mm) };
            *(f16x4*)&lds_n[node][f4 * 4] = h;   // byte addr node*40 + f4*8, 8-aligned
        }
        {
            const f32x4 v = *(const f32x4*)(xs + (size_t)(m0 + node) * 16 + f4 * 4);
            const float mm = ms[m0 + node];
            f16x4 h = { (_Float16)(v.x * mm), (_Float16)(v.y * mm),
                        (_Float16)(v.z * mm), (_Float16)(v.w * mm) };
            *(f16x4*)&lds_m[node][f4 * 4] = h;
        }
    }
    __syncthreads();

    // ---- Squared norms from the CONVERTED fp16 values (keeps cancellation exact) ----
    {
        const int node = tid & 127;
        const _Float16* p = (tid < 128) ? &lds_m[node][0] : &lds_n[node][0];
        float s = 0.0f;
        #pragma unroll
        for (int f4 = 0; f4 < 4; ++f4) {
            const f16x4 h = *(const f16x4*)&p[f4 * 4];
            const float a0 = (float)h.x, a1 = (float)h.y;
            const float a2 = (float)h.z, a3 = (float)h.w;
            s = fmaf(a0, a0, s); s = fmaf(a1, a1, s);
            s = fmaf(a2, a2, s); s = fmaf(a3, a3, s);
        }
        if (tid < 128) na_m[node] = s; else na_n[node] = s;
    }
    __syncthreads();

    // ---- MFMA Gram: wave w owns output cols m0+32w..+31, all 128 rows ----
    const int lane = tid & 63;
    const int wv   = tid >> 6;      // 0..3
    const int lr   = lane & 15;     // node-within-fragment
    const int q    = lane >> 4;     // k-quarter (and output sub-column group)
    const int mb   = wv * 32;

    // A-frags = m-nodes (operand swap), B-frags = n-nodes. Identical lane layout:
    // lane l -> node base+lr, features 4q..4q+3 -> one ds_read_b64 each.
    f16x4 afr[2];
    #pragma unroll
    for (int a = 0; a < 2; ++a)
        afr[a] = *(const f16x4*)&lds_m[mb + a * 16 + lr][q * 4];
    f16x4 bfr[8];
    #pragma unroll
    for (int b = 0; b < 8; ++b)
        bfr[b] = *(const f16x4*)&lds_n[b * 16 + lr][q * 4];

    f32x4 acc[8][2];
    #pragma unroll
    for (int b = 0; b < 8; ++b)
        #pragma unroll
        for (int a = 0; a < 2; ++a) {
            f32x4 z = {0.0f, 0.0f, 0.0f, 0.0f};
            // D[i=4q+r][j=lr] = sum_k A_hat[m0+mb+16a+i][k] * A_hat[n0+16b+j][k]
            acc[b][a] = __builtin_amdgcn_mfma_f32_16x16x16f16(afr[a], bfr[b], z, 0, 0, 0);
        }

    // Column norms for this lane's 4 output columns per a-frag (16B aligned)
    f32x4 nm[2];
    nm[0] = *(const f32x4*)&na_m[mb + q * 4];
    nm[1] = *(const f32x4*)&na_m[mb + 16 + q * 4];

    float* outs = out + (size_t)slice * (512 * 512) + (size_t)n0 * 512 + (m0 + mb);

    // ---- Fused epilogue + streaming stores: one f32x4 per (b,a) tile ----
    #pragma unroll
    for (int b = 0; b < 8; ++b) {
        const float nn = na_n[b * 16 + lr];              // LDS broadcast across quarters
        const size_t rowoff = (size_t)(b * 16 + lr) * 512;
        #pragma unroll
        for (int a = 0; a < 2; ++a) {
            f32x4 r;
            #pragma unroll
            for (int j = 0; j < 4; ++j) {
                float s = fmaf(-2.0f, acc[b][a][j], nn + nm[a][j]);
                s = fmaxf(s, EPS_F);
                const float d = __builtin_amdgcn_sqrtf(s);
                const float e = __builtin_amdgcn_exp2f(d * NEG_DIST_LOG2E);
                r[j] = fminf(e, 1.0f);   // CLIP_LOW=0 implied: e > 0 always
            }
            __builtin_nontemporal_store(r, (f32x4*)(outs + rowoff + a * 16 + q * 4));
        }
    }
}

extern "C" void kernel_launch(void* const* d_in, const int* in_sizes, int n_in,
                              void* d_out, int out_size, void* d_ws, size_t ws_size,
                              hipStream_t stream) {
    const float* x   = (const float*)d_in[0];   // (8,64,512,16) fp32
    const float* msk = (const float*)d_in[1];   // (8,64,512,1)  fp32
    float* out = (float*)d_out;                 // (8,64,512,512,1) fp32

    dim3 grid(16, 512);   // 16 tiles of 128x128 per slice, 512 slices
    node_pair_gaussian_kernel<<<grid, 256, 0, stream>>>(x, msk, out);
}

// Round 2
// 525.461 us; speedup vs baseline: 1.1446x; 1.1446x over previous
//
#include <hip/hip_runtime.h>

// out[b,k,n,m] = clip(exp(-0.1*sqrt(max(|An|^2 - 2 An.Am + |Am|^2, 1e-6))), 0, 1)
// x: (8,64,512,16) fp32, msk: (8,64,512,1) fp32, out: (8,64,512,512,1) fp32 (512 MiB).
//
// v3: write-contiguity retile. Evidence: v1 (4x256B segments/store, 512B-per-2KiB
// block streams) ran ~189 us kernel vs 85 us write floor; v2 (16x64B segments)
// ran ~256 us. Both fit "NT-write efficiency is set by stream contiguity".
//  - Block = 64 rows x 512 cols of one slice -> output region is one CONTIGUOUS
//    128 KiB stream. Each wave owns 8 full rows (16 KiB contiguous); every f32x4
//    store instruction writes 1024 B fully contiguous (64 lanes x 16 B).
//  - f32 VALU Gram (reverted from MFMA: its D-layout forces 64 B store segments).
//    Per-thread work unchanged vs v1: 8x8 register tile, 1024 FMA.
//  - Row fragments (an) are wave-uniform -> broadcast ds_read_b128 (free-ish);
//    only col fragments pay LDS bandwidth. LDS pipe busy ~halved vs v1.
//  - Norms folded into staging via 4-lane __shfl_xor reduce -> ONE __syncthreads.
//  - LDS strides 516/68: staging scatter-writes 2-way (free), fragment reads
//    throughput-minimal, all f32x4 reads 16 B aligned.
//  - grid(512,8): linear id = slice + 512*rowtile == slice (mod 8) -> all 8
//    row-blocks of a slice on the same XCD -> staging reads are L2-local.

typedef float f32x4 __attribute__((ext_vector_type(4)));

#define NEG_DIST_LOG2E (-0.14426950408889634f)  // -0.1 * log2(e)
#define EPS_F 1e-6f
#define LDM 516   // 512 + 4 pad: bank = (f*4 + node) % 32
#define LDN 68    // 64 + 4 pad

__global__ __launch_bounds__(512) void node_pair_gaussian_kernel(
    const float* __restrict__ x,    // (512 slices, 512 nodes, 16 f)
    const float* __restrict__ msk,  // (512 slices, 512 nodes)
    float* __restrict__ out)        // (512 slices, 512, 512)
{
    __shared__ __align__(16) float lds_m[16][LDM];  // full slice, [f][node]
    __shared__ __align__(16) float lds_n[16][LDN];  // 64-row tile, [f][node]
    __shared__ __align__(16) float na_m[512];
    __shared__ __align__(16) float na_n[64];

    const int tid   = threadIdx.x;       // 0..511
    const int slice = blockIdx.x;        // 0..511
    const int r0    = blockIdx.y << 6;   // row tile base: 0..448

    const float* xs = x   + (size_t)slice * (512 * 16);
    const float* ms = msk + (size_t)slice * 512;

    // ---- Stage full slice (col operand) transposed [f][node], masked; fold in
    //      squared-norm computation via 4-lane shuffle reduce ----
    #pragma unroll
    for (int it = 0; it < 4; ++it) {
        const int c    = tid + it * 512;          // 0..2047 = 512 nodes x 4 chunks
        const int node = c >> 2;
        const int f4   = (c & 3) * 4;
        const f32x4 v  = *(const f32x4*)(xs + (size_t)c * 4);  // coalesced
        const float mm = ms[node];
        lds_m[f4 + 0][node] = v.x * mm;
        lds_m[f4 + 1][node] = v.y * mm;
        lds_m[f4 + 2][node] = v.z * mm;
        lds_m[f4 + 3][node] = v.w * mm;
        // partial |A|^2 for this 4-feature chunk; 4 adjacent lanes hold one node
        float p = (v.x * v.x + v.y * v.y + v.z * v.z + v.w * v.w) * (mm * mm);
        p += __shfl_xor(p, 1);
        p += __shfl_xor(p, 2);
        if ((tid & 3) == 0) na_m[node] = p;
    }
    // ---- Stage 64-row tile (row operand) the same way ----
    if (tid < 256) {
        const int node = tid >> 2;                // 0..63
        const int f4   = (tid & 3) * 4;
        const f32x4 v  = *(const f32x4*)(xs + (size_t)(r0 + node) * 16 + f4);
        const float mm = ms[r0 + node];
        lds_n[f4 + 0][node] = v.x * mm;
        lds_n[f4 + 1][node] = v.y * mm;
        lds_n[f4 + 2][node] = v.z * mm;
        lds_n[f4 + 3][node] = v.w * mm;
        float p = (v.x * v.x + v.y * v.y + v.z * v.z + v.w * v.w) * (mm * mm);
        p += __shfl_xor(p, 1);
        p += __shfl_xor(p, 2);
        if ((tid & 3) == 0) na_n[node] = p;
    }
    __syncthreads();

    // ---- 8x8 register-tile Gram: wave owns 8 consecutive rows, lane owns
    //      cols lane*4..+3 and 256+lane*4..+3 ----
    const int lane = tid & 63;
    const int w8   = (tid >> 6) << 3;    // wave*8: this wave's row base (0..56)

    float acc[8][8];
    #pragma unroll
    for (int i = 0; i < 8; ++i)
        #pragma unroll
        for (int j = 0; j < 8; ++j) acc[i][j] = 0.0f;

    #pragma unroll
    for (int f = 0; f < 16; ++f) {
        const f32x4 a0 = *(const f32x4*)&lds_n[f][w8];        // broadcast reads
        const f32x4 a1 = *(const f32x4*)&lds_n[f][w8 + 4];
        const f32x4 b0 = *(const f32x4*)&lds_m[f][lane * 4];        // strided
        const f32x4 b1 = *(const f32x4*)&lds_m[f][256 + lane * 4];
        const float an[8] = {a0.x, a0.y, a0.z, a0.w, a1.x, a1.y, a1.z, a1.w};
        const float am[8] = {b0.x, b0.y, b0.z, b0.w, b1.x, b1.y, b1.z, b1.w};
        #pragma unroll
        for (int i = 0; i < 8; ++i)
            #pragma unroll
            for (int j = 0; j < 8; ++j)
                acc[i][j] = fmaf(an[i], am[j], acc[i][j]);
    }

    const f32x4 nn0 = *(const f32x4*)&na_n[w8];               // broadcast
    const f32x4 nn1 = *(const f32x4*)&na_n[w8 + 4];
    const f32x4 nm0 = *(const f32x4*)&na_m[lane * 4];
    const f32x4 nm1 = *(const f32x4*)&na_m[256 + lane * 4];
    const float nn[8] = {nn0.x, nn0.y, nn0.z, nn0.w, nn1.x, nn1.y, nn1.z, nn1.w};
    const float nm[8] = {nm0.x, nm0.y, nm0.z, nm0.w, nm1.x, nm1.y, nm1.z, nm1.w};

    // Block output = out[slice][r0 : r0+64][:], one contiguous 128 KiB region.
    float* outs = out + (size_t)slice * (512 * 512) + (size_t)r0 * 512;

    // ---- Fused epilogue + streaming stores: each instruction = 1024 B contiguous
    //      (lane-consecutive 16 B chunks), wave covers 8 full 2 KiB rows ----
    #pragma unroll
    for (int i = 0; i < 8; ++i) {
        float r[8];
        #pragma unroll
        for (int j = 0; j < 8; ++j) {
            float s = fmaf(-2.0f, acc[i][j], nn[i] + nm[j]);
            s = fmaxf(s, EPS_F);
            const float d = __builtin_amdgcn_sqrtf(s);
            const float e = __builtin_amdgcn_exp2f(d * NEG_DIST_LOG2E);
            r[j] = fminf(e, 1.0f);   // CLIP_LOW=0 implied: e > 0 always
        }
        f32x4 w0 = {r[0], r[1], r[2], r[3]};
        f32x4 w1 = {r[4], r[5], r[6], r[7]};
        float* rowp = outs + (size_t)(w8 + i) * 512;
        __builtin_nontemporal_store(w0, (f32x4*)(rowp + lane * 4));
        __builtin_nontemporal_store(w1, (f32x4*)(rowp + 256 + lane * 4));
    }
}

extern "C" void kernel_launch(void* const* d_in, const int* in_sizes, int n_in,
                              void* d_out, int out_size, void* d_ws, size_t ws_size,
                              hipStream_t stream) {
    const float* x   = (const float*)d_in[0];   // (8,64,512,16) fp32
    const float* msk = (const float*)d_in[1];   // (8,64,512,1)  fp32
    float* out = (float*)d_out;                 // (8,64,512,512,1) fp32

    // x = slice, y = row-tile: linear id == slice (mod 8) -> per-slice XCD affinity
    dim3 grid(512, 8);
    node_pair_gaussian_kernel<<<grid, 512, 0, stream>>>(x, msk, out);
}